// Round 6
// baseline (283.366 us; speedup 1.0000x reference)
//
#include <hip/hip_runtime.h>
#include <hip/hip_bf16.h>

typedef unsigned short ushort_t;
typedef __bf16 bf16x8 __attribute__((ext_vector_type(8)));
typedef unsigned short us8 __attribute__((ext_vector_type(8)));
typedef float f32x4 __attribute__((ext_vector_type(4)));

__device__ __forceinline__ float b2f(ushort_t h) {
    union { unsigned int u; float f; } v; v.u = ((unsigned int)h) << 16; return v.f;
}
__device__ __forceinline__ ushort_t f2b(float f) {
    union { float f; unsigned int u; } v; v.f = f;
    unsigned int u = v.u;
    unsigned int r = (u + 0x7FFFu + ((u >> 16) & 1u)) >> 16;
    return (ushort_t)r;
}
__device__ __forceinline__ float sigmoidf_(float x) {
    return 1.f / (1.f + __expf(-x));
}
__device__ __forceinline__ void store_o(ushort_t* p, float v) { *p = f2b(v); }
__device__ __forceinline__ void store_o(float* p, float v) { *p = v; }

__global__ void fill_kernel(float* out, long long n, float val) {
    long long i = (long long)blockIdx.x * blockDim.x + threadIdx.x;
    if (i < n) out[i] = val;
}

// ---------------------------------------------------------------------------
// Packed B layout for mfma_f32_16x16x32_bf16 (per 64-col block c, 32-k group
// kk): 4 col-subtiles su, 64 lanes (lane = k-oct*16 + col&15), 8 bf16.
// Tile (c,kk) = 2048 ushorts; wave fragment load = 1 KB contiguous.
// ---------------------------------------------------------------------------
#define PACKSZ(O, K) ((long long)((O) >= 64 ? (O) >> 6 : 1) * ((K) >> 5) * 2048)

// ---------------------------------------------------------------------------
// Ballot-based sort: 1 block, 1024 thr (16 waves x 512 elems). No atomic
// contention: per-wave histograms + in-wave ranks via ballot/popc.
// ---------------------------------------------------------------------------
__global__ void sort_kernel(const int* __restrict__ ids, int N,
                            int* __restrict__ perm, int* __restrict__ seg,
                            int4* __restrict__ ttab, int* __restrict__ tcount) {
    __shared__ int hist[16][8];
    __shared__ int wbase[16][8];
    __shared__ int atot[8];
    __shared__ int abase[8];
    int tid = threadIdx.x, wave = tid >> 6, lane = tid & 63;
    int base = wave * 512;
    unsigned long long lt = (lane == 63) ? 0x7fffffffffffffffull
                                         : ((1ull << lane) - 1ull);
    int myid[8], rank[8];
    int run[8] = {0, 0, 0, 0, 0, 0, 0, 0};
    #pragma unroll
    for (int i = 0; i < 8; i++) myid[i] = ids[base + i * 64 + lane] & 7;
    #pragma unroll
    for (int i = 0; i < 8; i++) {
        int a = myid[i];
        int r = 0;
        #pragma unroll
        for (int a2 = 0; a2 < 8; a2++) {
            unsigned long long m = __ballot(a == a2);
            if (a2 == a) r = run[a2] + __popcll(m & lt);
            run[a2] += __popcll(m);
        }
        rank[i] = r;
    }
    if (lane == 0) {
        #pragma unroll
        for (int a = 0; a < 8; a++) hist[wave][a] = run[a];
    }
    __syncthreads();
    if (tid < 8) {
        int a = tid, s = 0;
        for (int w = 0; w < 16; w++) { wbase[w][a] = s; s += hist[w][a]; }
        atot[a] = s;
    }
    __syncthreads();
    if (tid == 0) {
        int s = 0;
        for (int a = 0; a < 8; a++) { abase[a] = s; seg[a] = s; s += atot[a]; }
        seg[8] = s;
        int T = 0;
        for (int a = 0; a < 8; a++)
            for (int m = abase[a]; m < abase[a] + atot[a]; m += 64) {
                int e = abase[a] + atot[a];
                if (e > m + 64) e = m + 64;
                ttab[T++] = make_int4(a, m, e, 0);
            }
        *tcount = T;
    }
    __syncthreads();
    #pragma unroll
    for (int i = 0; i < 8; i++) {
        int a = myid[i];
        perm[abase[a] + wbase[wave][a] + rank[i]] = base + i * 64 + lane;
    }
}

// ---------------------------------------------------------------------------
// Fused prep: masked weights -> packed-B bf16; activations gathered to
// pos-order bf16; GRU weights -> packed-B bf16.
// ---------------------------------------------------------------------------
__device__ __forceinline__ void maskw_item(const float* __restrict__ alpha,
                                           const float* __restrict__ w,
                                           ushort_t* __restrict__ wm,
                                           long long idx, int O, int G, int dup) {
    int g = (int)(idx % G);
    long long t2 = idx / G;
    int o = (int)(t2 % O);
    int a = (int)(t2 / O);
    const float* al = alpha + idx * 6;
    float p[6];
    float mx = -1e30f;
    #pragma unroll
    for (int i = 0; i < 6; i++) { p[i] = al[i] * 0.2f; mx = fmaxf(mx, p[i]); }
    float s = 0.f;
    #pragma unroll
    for (int i = 0; i < 6; i++) { p[i] = __expf(p[i] - mx); s += p[i]; }
    float inv = 1.f / s;
    #pragma unroll
    for (int i = 0; i < 6; i++) p[i] *= inv;
    float mk[4] = { p[0] + p[1] + p[2], p[0] + p[3] + p[4],
                    p[1] + p[3] + p[5], p[2] + p[4] + p[5] };
    int K = G * 4;
    const float* wr = w + (long long)o * K + g * 4;
    ushort_t* base = wm + (long long)a * PACKSZ(O, K);
    int k0 = g * 4;
    int c = o >> 6, su = (o >> 4) & 3, n = o & 15;
    int kk = k0 >> 5, q = (k0 >> 3) & 3, e0 = k0 & 7;
    long long off = (((long long)(c * (K >> 5) + kk) * 4 + su) * 64 + (q * 16 + n)) * 8 + e0;
    #pragma unroll
    for (int t = 0; t < 4; t++) {
        ushort_t v = f2b(wr[t] * mk[t]);
        base[off + t] = v;
        if (dup) {
            base[off + t + 512] = v;
            base[off + t + 1024] = v;
            base[off + t + 1536] = v;
        }
    }
}

__device__ __forceinline__ void canon_gather_item(const float* __restrict__ src,
                                                  ushort_t* __restrict__ dst,
                                                  const int* __restrict__ perm,
                                                  int ld, long long i) {
    long long base = i * 8;
    int pos = (int)(base / ld);
    int k = (int)(base % ld);
    int row = perm[pos] & 8191;
    const float* s = src + (long long)row * ld + k;
    us8 v;
    #pragma unroll
    for (int e = 0; e < 8; e++) v[e] = f2b(s[e]);
    *(us8*)(dst + base) = v;
}

__device__ __forceinline__ void canon_pack_item(const float* __restrict__ src,
                                                ushort_t* __restrict__ dst,
                                                long long i) {
    long long base = i * 8;
    int o_full = (int)(base >> 9);
    int k0 = (int)(base & 511);
    int g = o_full >> 9, o = o_full & 511;
    int c = o >> 6, su = (o >> 4) & 3, n = o & 15;
    int kk = k0 >> 5, q = (k0 >> 3) & 3;
    long long off = (long long)g * 262144 +
        (((long long)(c * 16 + kk) * 4 + su) * 64 + (q * 16 + n)) * 8;
    us8 v;
    #pragma unroll
    for (int e = 0; e < 8; e++) v[e] = f2b(src[base + e]);
    *(us8*)(dst + off) = v;
}

#define PB0 256
#define PB1 2048
#define PB2 2048
#define PB3 64
#define PB4 256
#define PB5 2048
#define PB6 384
#define PB7 384
#define PREP_BLOCKS (PB0+PB1+PB2+PB3+PB4+PB5+PB6+PB7)

__global__ void prep_kernel(const float* fc1_al, const float* fc1_w, ushort_t* wm1,
                            const float* fc2_al, const float* fc2_w, ushort_t* wm2,
                            const float* fc3_al, const float* fc3_w, ushort_t* wm3,
                            const float* fc4_al, const float* fc4_w, ushort_t* wm4,
                            const float* inputs, ushort_t* inp_pos,
                            const float* hidden, ushort_t* hid_pos,
                            const float* wih, ushort_t* wihp,
                            const float* whh, ushort_t* whhp,
                            const int* perm) {
    int b = blockIdx.x;
    int tid = threadIdx.x;
    if (b < PB0) { maskw_item(fc1_al, fc1_w, wm1, (long long)b * 256 + tid, 512, 16, 0); return; }
    b -= PB0;
    if (b < PB1) { maskw_item(fc2_al, fc2_w, wm2, (long long)b * 256 + tid, 512, 128, 0); return; }
    b -= PB1;
    if (b < PB2) { maskw_item(fc3_al, fc3_w, wm3, (long long)b * 256 + tid, 512, 128, 0); return; }
    b -= PB2;
    if (b < PB3) { maskw_item(fc4_al, fc4_w, wm4, (long long)b * 256 + tid, 16, 128, 1); return; }
    b -= PB3;
    if (b < PB4) { canon_gather_item(inputs, inp_pos, perm, 64, (long long)b * 256 + tid); return; }
    b -= PB4;
    if (b < PB5) { canon_gather_item(hidden, hid_pos, perm, 512, (long long)b * 256 + tid); return; }
    b -= PB5;
    if (b < PB6) { canon_pack_item(wih, wihp, (long long)b * 256 + tid); return; }
    b -= PB6;
    canon_pack_item(whh, whhp, (long long)b * 256 + tid);
}

// ---------------------------------------------------------------------------
// GEMM: A staged via swizzled LDS; B streamed from packed global (L2).
// Baseline 2-barrier structure (proven best so far); occupancy raised:
// LDS 4 KB + VGPR<=64 -> 8 blocks/CU for latency hiding (was 4).
// ---------------------------------------------------------------------------
#define BM 64
#define BN 64

template <typename OT>
__launch_bounds__(256, 8)
__global__ void gemm_tiled(const ushort_t* __restrict__ In, int ldin,
                           const ushort_t* __restrict__ Wpk, long long wstride,
                           const float* __restrict__ bias,
                           OT* __restrict__ Out, int ldo,
                           const int4* __restrict__ ttab,
                           const int* __restrict__ tcount,
                           const int* __restrict__ scatter,
                           int O, int K, int relu) {
    int t = blockIdx.x;
    if (t >= *tcount) return;
    int4 tt = ttab[t];
    int a = tt.x, pos0 = tt.y, pos1 = tt.z;
    int o0 = blockIdx.y * BN;

    __shared__ ushort_t As[2048];

    int tid = threadIdx.x;
    int wave = tid >> 6, lane = tid & 63;
    int wr = (wave >> 1) & 1, wc = wave & 1;
    int quad = lane >> 4, l16 = lane & 15;
    int srow = tid >> 2, sgrp = tid & 3;
    int wsoff = (srow * 4 + (sgrp ^ ((srow >> 2) & 3))) * 8;
    int rl = (l16 * 4 + (quad ^ ((l16 >> 2) & 3))) * 8;

    int apos = pos0 + srow;
    int apos_c = apos < pos1 ? apos : (pos1 - 1);
    const ushort_t* aptr = In + (long long)apos_c * ldin + sgrp * 8;

    const ushort_t* wb = Wpk + (long long)a * wstride +
        (long long)blockIdx.y * (K >> 5) * 2048 + lane * 8;

    f32x4 acc[2][2];
    #pragma unroll
    for (int i = 0; i < 2; i++)
        #pragma unroll
        for (int j = 0; j < 2; j++) acc[i][j] = (f32x4){0.f, 0.f, 0.f, 0.f};

    int KK = K >> 5;
    for (int kk = 0; kk < KK; kk++) {
        us8 av = *(const us8*)(aptr + kk * 32);
        bf16x8 bfr[2];
        bfr[0] = *(const bf16x8*)(wb + (kk * 4 + wc * 2 + 0) * 512);
        bfr[1] = *(const bf16x8*)(wb + (kk * 4 + wc * 2 + 1) * 512);
        __syncthreads();
        *(us8*)(&As[wsoff]) = av;
        __syncthreads();
        bf16x8 af[2];
        af[0] = *(const bf16x8*)(&As[(wr * 2 + 0) * 512 + rl]);
        af[1] = *(const bf16x8*)(&As[(wr * 2 + 1) * 512 + rl]);
        #pragma unroll
        for (int i = 0; i < 2; i++)
            #pragma unroll
            for (int j = 0; j < 2; j++)
                acc[i][j] = __builtin_amdgcn_mfma_f32_16x16x32_bf16(af[i], bfr[j], acc[i][j], 0, 0, 0);
    }

    #pragma unroll
    for (int i = 0; i < 2; i++) {
        int mbase = wr * 32 + i * 16 + quad * 4;
        #pragma unroll
        for (int j = 0; j < 2; j++) {
            int col = o0 + wc * 32 + j * 16 + l16;
            if (col < O) {
                float bias_v = bias ? bias[col] : 0.f;
                #pragma unroll
                for (int r = 0; r < 4; r++) {
                    int pos = pos0 + mbase + r;
                    if (pos < pos1) {
                        float v = acc[i][j][r] + bias_v;
                        if (relu) v = fmaxf(v, 0.f);
                        int orow = (scatter ? scatter[pos] : pos) & 8191;
                        store_o(&Out[(long long)orow * ldo + col], v);
                    }
                }
            }
        }
    }
}

// ---------------------------------------------------------------------------
// Fused GRU, 4 accumulator groups (r/z gates sum both GEMMs into one acc):
//   acc0 = y1.wih_r + h.whh_r ; acc1 = y1.wih_z + h.whh_z
//   acc2 = y1.wih_n           ; acc3 = h.whh_n
// Baseline 2-barrier structure; occupancy raised: LDS 32 KB allows exactly
// 5 blocks/CU (was capped at 3 by launch_bounds).
// ---------------------------------------------------------------------------
__launch_bounds__(256, 5)
__global__ void gru_fused(const ushort_t* __restrict__ y1,       // [N,H] pos bf16
                          const ushort_t* __restrict__ hid_pos,  // [N,H] pos bf16
                          const float* __restrict__ hidden_f,    // [N,H] orig fp32
                          const ushort_t* __restrict__ wihp,     // packed 3x(512,512)
                          const ushort_t* __restrict__ whhp,     // packed 3x(512,512)
                          const float* __restrict__ bih,
                          const float* __restrict__ bhh,
                          const int* __restrict__ perm,
                          float* __restrict__ out_h_f,           // [N,H] orig fp32
                          ushort_t* __restrict__ hp,             // [N,H] pos bf16
                          int N, int H) {
    int m0 = blockIdx.x * 64;

    __shared__ ushort_t Ay[2048];
    __shared__ ushort_t Ah[2048];
    __shared__ ushort_t Bt[6][2048];

    int tid = threadIdx.x;
    int wave = tid >> 6, lane = tid & 63;
    int wr = (wave >> 1) & 1, wc = wave & 1;
    int quad = lane >> 4, l16 = lane & 15;
    int srow = tid >> 2, sgrp = tid & 3;
    int wsoff = (srow * 4 + (sgrp ^ ((srow >> 2) & 3))) * 8;
    int rl = (l16 * 4 + (quad ^ ((l16 >> 2) & 3))) * 8;

    const ushort_t* ay_p = y1 + (long long)(m0 + srow) * H + sgrp * 8;
    const ushort_t* ah_p = hid_pos + (long long)(m0 + srow) * H + sgrp * 8;

    // packed B tile stream bases (c-block = blockIdx.y): tile(kk) at kk*2048
    long long cb = (long long)blockIdx.y * 16 * 2048 + tid * 8;
    const ushort_t* wbg[6];
    #pragma unroll
    for (int g = 0; g < 3; g++) wbg[g] = wihp + (long long)g * 262144 + cb;
    #pragma unroll
    for (int g = 3; g < 6; g++) wbg[g] = whhp + (long long)(g - 3) * 262144 + cb;

    f32x4 acc[4][2][2];
    #pragma unroll
    for (int g = 0; g < 4; g++)
        #pragma unroll
        for (int i = 0; i < 2; i++)
            #pragma unroll
            for (int j = 0; j < 2; j++) acc[g][i][j] = (f32x4){0.f, 0.f, 0.f, 0.f};

    for (int kk = 0; kk < 16; kk++) {
        us8 va = *(const us8*)(ay_p + kk * 32);
        us8 vh = *(const us8*)(ah_p + kk * 32);
        us8 vb[6];
        #pragma unroll
        for (int g = 0; g < 6; g++) vb[g] = *(const us8*)(wbg[g] + kk * 2048);
        __syncthreads();
        *(us8*)(&Ay[wsoff]) = va;
        *(us8*)(&Ah[wsoff]) = vh;
        #pragma unroll
        for (int g = 0; g < 6; g++) *(us8*)(&Bt[g][tid * 8]) = vb[g];
        __syncthreads();

        bf16x8 ayf[2], ahf[2];
        #pragma unroll
        for (int u = 0; u < 2; u++) {
            ayf[u] = *(const bf16x8*)(&Ay[(wr * 2 + u) * 512 + rl]);
            ahf[u] = *(const bf16x8*)(&Ah[(wr * 2 + u) * 512 + rl]);
        }
        #pragma unroll
        for (int g = 0; g < 3; g++) {
            bf16x8 bw[2], bu[2];
            #pragma unroll
            for (int u = 0; u < 2; u++) {
                bw[u] = *(const bf16x8*)(&Bt[g][(wc * 2 + u) * 512 + lane * 8]);
                bu[u] = *(const bf16x8*)(&Bt[g + 3][(wc * 2 + u) * 512 + lane * 8]);
            }
            int ai = (g < 2) ? g : 2;   // ih products: r->0, z->1, n->2
            int ah2 = (g < 2) ? g : 3;  // hh products: r->0, z->1, n->3
            #pragma unroll
            for (int i = 0; i < 2; i++)
                #pragma unroll
                for (int j = 0; j < 2; j++) {
                    acc[ai][i][j] = __builtin_amdgcn_mfma_f32_16x16x32_bf16(
                        ayf[i], bw[j], acc[ai][i][j], 0, 0, 0);
                    acc[ah2][i][j] = __builtin_amdgcn_mfma_f32_16x16x32_bf16(
                        ahf[i], bu[j], acc[ah2][i][j], 0, 0, 0);
                }
        }
    }

    int c0 = blockIdx.y * 64;
    #pragma unroll
    for (int i = 0; i < 2; i++) {
        #pragma unroll
        for (int r = 0; r < 4; r++) {
            int pos = m0 + wr * 32 + i * 16 + quad * 4 + r;
            int norig = perm[pos] & 8191;
            #pragma unroll
            for (int j = 0; j < 2; j++) {
                int col = c0 + wc * 32 + j * 16 + l16;
                float sr = acc[0][i][j][r] + bih[col] + bhh[col];
                float sz = acc[1][i][j][r] + bih[H + col] + bhh[H + col];
                float in_ = acc[2][i][j][r] + bih[2 * H + col];
                float hn = acc[3][i][j][r] + bhh[2 * H + col];
                float rg = sigmoidf_(sr);
                float zg = sigmoidf_(sz);
                float ng = tanhf(in_ + rg * hn);
                float hv = hidden_f[(long long)norig * H + col];
                float hnew = (1.f - zg) * ng + zg * hv;
                out_h_f[(long long)norig * H + col] = hnew;
                hp[(long long)pos * H + col] = f2b(hnew);
            }
        }
    }
}

// ---------------------------------------------------------------------------
extern "C" void kernel_launch(void* const* d_in, const int* in_sizes, int n_in,
                              void* d_out, int out_size, void* d_ws, size_t ws_size,
                              hipStream_t stream) {
    (void)in_sizes; (void)n_in;
    const int N = 8192, A = 8, E = 64, H = 512, NA = 16;

    float* out_f = (float*)d_out;
    float* out_q = out_f;                        // [N, NA] fp32
    float* out_h = out_f + (size_t)N * NA;       // [N, H] fp32, original order

    char* p = (char*)d_ws;
    auto alloc = [&](size_t b) { char* r = p; p += (b + 255) & ~(size_t)255; return r; };
    int*  perm   = (int*)alloc((size_t)N * 4);
    int*  seg    = (int*)alloc(16 * 4);
    int4* ttab   = (int4*)alloc(144 * 16);
    int*  tcount = (int*)alloc(256);
    ushort_t* wm1     = (ushort_t*)alloc((size_t)A * PACKSZ(H, E) * 2);
    ushort_t* wm2     = (ushort_t*)alloc((size_t)A * PACKSZ(H, H) * 2);
    ushort_t* wm3     = (ushort_t*)alloc((size_t)A * PACKSZ(H, H) * 2);
    ushort_t* wm4     = (ushort_t*)alloc((size_t)A * PACKSZ(NA, H) * 2);
    ushort_t* y1      = (ushort_t*)alloc((size_t)N * H * 2);
    ushort_t* inp_pos = (ushort_t*)alloc((size_t)N * E * 2);
    ushort_t* hid_pos = (ushort_t*)alloc((size_t)N * H * 2);
    ushort_t* wihp    = (ushort_t*)alloc((size_t)3 * H * H * 2);
    ushort_t* whhp    = (ushort_t*)alloc((size_t)3 * H * H * 2);
    ushort_t* hp      = (ushort_t*)alloc((size_t)N * H * 2);
    size_t need = (size_t)(p - (char*)d_ws);
    ushort_t* q2 = y1;       // alias: y1 dead after gru_fused
    ushort_t* q3 = hid_pos;  // alias: hid_pos dead after gru_fused

    if (ws_size < need) {
        fill_kernel<<<(unsigned)((out_size + 255) / 256), 256, 0, stream>>>(
            out_f, out_size, 1000.f);
        return;
    }

    const float* inputs = (const float*)d_in[0];
    const float* hidden = (const float*)d_in[1];
    const int*   ids    = (const int*)d_in[2];
    const float* fc1_w  = (const float*)d_in[3];
    const float* fc1_b  = (const float*)d_in[4];
    const float* fc1_al = (const float*)d_in[5];
    const float* wih    = (const float*)d_in[6];
    const float* whh    = (const float*)d_in[7];
    const float* bih    = (const float*)d_in[8];
    const float* bhh    = (const float*)d_in[9];
    const float* fc2_w  = (const float*)d_in[10];
    const float* fc2_b  = (const float*)d_in[11];
    const float* fc2_al = (const float*)d_in[12];
    const float* fc3_w  = (const float*)d_in[13];
    const float* fc3_b  = (const float*)d_in[14];
    const float* fc3_al = (const float*)d_in[15];
    const float* fc4_w  = (const float*)d_in[16];
    const float* fc4_b  = (const float*)d_in[17];
    const float* fc4_al = (const float*)d_in[18];

    sort_kernel<<<1, 1024, 0, stream>>>(ids, N, perm, seg, ttab, tcount);

    prep_kernel<<<PREP_BLOCKS, 256, 0, stream>>>(
        fc1_al, fc1_w, wm1, fc2_al, fc2_w, wm2, fc3_al, fc3_w, wm3,
        fc4_al, fc4_w, wm4, inputs, inp_pos, hidden, hid_pos,
        wih, wihp, whh, whhp, perm);

    dim3 blk(256);
    gemm_tiled<ushort_t><<<dim3(136, H / BN), blk, 0, stream>>>(
        inp_pos, E, wm1, PACKSZ(H, E), fc1_b, y1, H, ttab, tcount,
        nullptr, H, E, 1);
    gru_fused<<<dim3(N / 64, H / 64), blk, 0, stream>>>(
        y1, hid_pos, hidden, wihp, whhp, bih, bhh, perm, out_h, hp, N, H);
    gemm_tiled<ushort_t><<<dim3(136, H / BN), blk, 0, stream>>>(
        hp, H, wm2, PACKSZ(H, H), fc2_b, q2, H, ttab, tcount,
        nullptr, H, H, 1);
    gemm_tiled<ushort_t><<<dim3(136, H / BN), blk, 0, stream>>>(
        q2, H, wm3, PACKSZ(H, H), fc3_b, q3, H, ttab, tcount,
        nullptr, H, H, 1);
    gemm_tiled<float><<<dim3(136, 1), blk, 0, stream>>>(
        q3, H, wm4, PACKSZ(NA, H), fc4_b, out_q, NA, ttab, tcount,
        perm, NA, H, 0);
}

// Round 7
// 239.567 us; speedup vs baseline: 1.1828x; 1.1828x over previous
//
#include <hip/hip_runtime.h>
#include <hip/hip_bf16.h>

typedef unsigned short ushort_t;
typedef __bf16 bf16x8 __attribute__((ext_vector_type(8)));
typedef unsigned short us8 __attribute__((ext_vector_type(8)));
typedef float f32x4 __attribute__((ext_vector_type(4)));

#define NPAD 8704
#define SENT (1 << 20)

__device__ __forceinline__ ushort_t f2b(float f) {
    union { float f; unsigned int u; } v; v.f = f;
    unsigned int u = v.u;
    unsigned int r = (u + 0x7FFFu + ((u >> 16) & 1u)) >> 16;
    return (ushort_t)r;
}
__device__ __forceinline__ float sigmoidf_(float x) {
    return 1.f / (1.f + __expf(-x));
}

// global->LDS direct DMA, 16 B per lane. LDS dest wave-uniform; HW adds lane*16.
__device__ __forceinline__ void gl16(const ushort_t* g, ushort_t* l) {
    __builtin_amdgcn_global_load_lds(
        (const __attribute__((address_space(1))) unsigned int*)g,
        (__attribute__((address_space(3))) unsigned int*)l, 16, 0, 0);
}
__device__ __forceinline__ void vm0_bar() {
    asm volatile("s_waitcnt vmcnt(0)" ::: "memory");
    __builtin_amdgcn_s_barrier();
    __builtin_amdgcn_sched_barrier(0);
}

__global__ void fill_kernel(float* out, long long n, float val) {
    long long i = (long long)blockIdx.x * blockDim.x + threadIdx.x;
    if (i < n) out[i] = val;
}

// ---------------------------------------------------------------------------
// Packed B layout (per 64-col block c, 32-k group kk): 4 col-subtiles su,
// 64 lanes, 8 bf16 -> tile = 2048 ushorts, fragment = 1 KB lane-linear.
// Packed A layout: tile (mt = pos/16, kk): lane l holds row l&15, k-oct l>>4,
// 8 contiguous bf16 -> fragment = 512 ushorts, lane-linear.
// ---------------------------------------------------------------------------
#define PACKSZ(O, K) ((long long)((O) >= 64 ? (O) >> 6 : 1) * ((K) >> 5) * 2048)

// ---------------------------------------------------------------------------
// Ballot-based sort with 64-PADDED segments; dummy positions perm = SENT.
// ---------------------------------------------------------------------------
__global__ void sort_kernel(const int* __restrict__ ids, int N,
                            int* __restrict__ perm, int* __restrict__ seg,
                            int4* __restrict__ ttab, int* __restrict__ tcount) {
    __shared__ int hist[16][8];
    __shared__ int wbase[16][8];
    __shared__ int atot[8];
    __shared__ int abase[8];
    int tid = threadIdx.x, wave = tid >> 6, lane = tid & 63;
    int base = wave * 512;
    unsigned long long lt = (lane == 63) ? 0x7fffffffffffffffull
                                         : ((1ull << lane) - 1ull);
    int myid[8], rank[8];
    int run[8] = {0, 0, 0, 0, 0, 0, 0, 0};
    #pragma unroll
    for (int i = 0; i < 8; i++) myid[i] = ids[base + i * 64 + lane] & 7;
    #pragma unroll
    for (int i = 0; i < 8; i++) {
        int a = myid[i];
        int r = 0;
        #pragma unroll
        for (int a2 = 0; a2 < 8; a2++) {
            unsigned long long m = __ballot(a == a2);
            if (a2 == a) r = run[a2] + __popcll(m & lt);
            run[a2] += __popcll(m);
        }
        rank[i] = r;
    }
    if (lane == 0) {
        #pragma unroll
        for (int a = 0; a < 8; a++) hist[wave][a] = run[a];
    }
    __syncthreads();
    if (tid < 8) {
        int a = tid, s = 0;
        for (int w = 0; w < 16; w++) { wbase[w][a] = s; s += hist[w][a]; }
        atot[a] = s;
    }
    __syncthreads();
    if (tid == 0) {
        int s = 0;
        for (int a = 0; a < 8; a++) {
            abase[a] = s; seg[a] = s;
            s += (atot[a] + 63) & ~63;      // padded segment
        }
        seg[8] = s;
        int T = 0;
        for (int a = 0; a < 8; a++) {
            int e = abase[a] + atot[a];
            int pe = abase[a] + ((atot[a] + 63) & ~63);
            for (int m = abase[a]; m < pe; m += 64) {
                int z = e < m + 64 ? e : m + 64;
                ttab[T++] = make_int4(a, m, z, 0);
            }
        }
        *tcount = T;
    }
    __syncthreads();
    #pragma unroll
    for (int i = 0; i < 8; i++) {
        int a = myid[i];
        perm[abase[a] + wbase[wave][a] + rank[i]] = base + i * 64 + lane;
    }
    for (int a = 0; a < 8; a++) {
        int e = abase[a] + atot[a];
        int pe = abase[a] + ((atot[a] + 63) & ~63);
        for (int p2 = e + tid; p2 < pe; p2 += 1024) perm[p2] = SENT;
    }
    int Pend = abase[7] + ((atot[7] + 63) & ~63);
    for (int p2 = Pend + tid; p2 < NPAD; p2 += 1024) perm[p2] = SENT;
}

// ---------------------------------------------------------------------------
// Fused prep.
// ---------------------------------------------------------------------------
__device__ __forceinline__ void maskw_item(const float* __restrict__ alpha,
                                           const float* __restrict__ w,
                                           ushort_t* __restrict__ wm,
                                           long long idx, int O, int G, int dup) {
    int g = (int)(idx % G);
    long long t2 = idx / G;
    int o = (int)(t2 % O);
    int a = (int)(t2 / O);
    const float* al = alpha + idx * 6;
    float p[6];
    float mx = -1e30f;
    #pragma unroll
    for (int i = 0; i < 6; i++) { p[i] = al[i] * 0.2f; mx = fmaxf(mx, p[i]); }
    float s = 0.f;
    #pragma unroll
    for (int i = 0; i < 6; i++) { p[i] = __expf(p[i] - mx); s += p[i]; }
    float inv = 1.f / s;
    #pragma unroll
    for (int i = 0; i < 6; i++) p[i] *= inv;
    float mk[4] = { p[0] + p[1] + p[2], p[0] + p[3] + p[4],
                    p[1] + p[3] + p[5], p[2] + p[4] + p[5] };
    int K = G * 4;
    const float* wr = w + (long long)o * K + g * 4;
    ushort_t* base = wm + (long long)a * PACKSZ(O, K);
    int k0 = g * 4;
    int c = o >> 6, su = (o >> 4) & 3, n = o & 15;
    int kk = k0 >> 5, q = (k0 >> 3) & 3, e0 = k0 & 7;
    long long off = (((long long)(c * (K >> 5) + kk) * 4 + su) * 64 + (q * 16 + n)) * 8 + e0;
    #pragma unroll
    for (int t = 0; t < 4; t++) {
        ushort_t v = f2b(wr[t] * mk[t]);
        base[off + t] = v;
        if (dup) {
            base[off + t + 512] = v;
            base[off + t + 1024] = v;
            base[off + t + 1536] = v;
        }
    }
}

__device__ __forceinline__ void canon_gather_packed(const float* __restrict__ src,
                                                    ushort_t* __restrict__ dst,
                                                    const int* __restrict__ perm,
                                                    int ld, long long i) {
    int l = (int)(i & 63);
    int tt = (int)(i >> 6);
    int KK = ld >> 5;
    int mt = tt / KK, kk = tt - mt * KK;
    int row = perm[mt * 16 + (l & 15)];
    if (row >= 8192) row = 0;
    const float* s = src + (long long)row * ld + kk * 32 + (l >> 4) * 8;
    us8 v;
    #pragma unroll
    for (int e = 0; e < 8; e++) v[e] = f2b(s[e]);
    *(us8*)(dst + i * 8) = v;
}

__device__ __forceinline__ void canon_pack_item(const float* __restrict__ src,
                                                ushort_t* __restrict__ dst,
                                                long long i) {
    long long base = i * 8;
    int o_full = (int)(base >> 9);
    int k0 = (int)(base & 511);
    int g = o_full >> 9, o = o_full & 511;
    int c = o >> 6, su = (o >> 4) & 3, n = o & 15;
    int kk = k0 >> 5, q = (k0 >> 3) & 3;
    long long off = (long long)g * 262144 +
        (((long long)(c * 16 + kk) * 4 + su) * 64 + (q * 16 + n)) * 8;
    us8 v;
    #pragma unroll
    for (int e = 0; e < 8; e++) v[e] = f2b(src[base + e]);
    *(us8*)(dst + off) = v;
}

#define PB0 256
#define PB1 2048
#define PB2 2048
#define PB3 64
#define PB4 272
#define PB5 2176
#define PB6 384
#define PB7 384
#define PREP_BLOCKS (PB0+PB1+PB2+PB3+PB4+PB5+PB6+PB7)

__global__ void prep_kernel(const float* fc1_al, const float* fc1_w, ushort_t* wm1,
                            const float* fc2_al, const float* fc2_w, ushort_t* wm2,
                            const float* fc3_al, const float* fc3_w, ushort_t* wm3,
                            const float* fc4_al, const float* fc4_w, ushort_t* wm4,
                            const float* inputs, ushort_t* inp_pos,
                            const float* hidden, ushort_t* hid_pos,
                            const float* wih, ushort_t* wihp,
                            const float* whh, ushort_t* whhp,
                            const int* perm) {
    int b = blockIdx.x;
    int tid = threadIdx.x;
    if (b < PB0) { maskw_item(fc1_al, fc1_w, wm1, (long long)b * 256 + tid, 512, 16, 0); return; }
    b -= PB0;
    if (b < PB1) { maskw_item(fc2_al, fc2_w, wm2, (long long)b * 256 + tid, 512, 128, 0); return; }
    b -= PB1;
    if (b < PB2) { maskw_item(fc3_al, fc3_w, wm3, (long long)b * 256 + tid, 512, 128, 0); return; }
    b -= PB2;
    if (b < PB3) { maskw_item(fc4_al, fc4_w, wm4, (long long)b * 256 + tid, 16, 128, 1); return; }
    b -= PB3;
    if (b < PB4) { canon_gather_packed(inputs, inp_pos, perm, 64, (long long)b * 256 + tid); return; }
    b -= PB4;
    if (b < PB5) { canon_gather_packed(hidden, hid_pos, perm, 512, (long long)b * 256 + tid); return; }
    b -= PB5;
    if (b < PB6) { canon_pack_item(wih, wihp, (long long)b * 256 + tid); return; }
    b -= PB6;
    canon_pack_item(whh, whhp, (long long)b * 256 + tid);
}

// ---------------------------------------------------------------------------
// GEMM (R5 structure, measured best for fc chain): global_load_lds double-
// buffer, 2-phase, packed-A in / packed-A out (PACKOUT) or scatter (fc4).
// ---------------------------------------------------------------------------
template <typename OT, int NC, int PACKOUT>
__launch_bounds__(256, 3)
__global__ void gemm_tiled(const ushort_t* __restrict__ Apk, int K,
                           const ushort_t* __restrict__ Wpk, long long wstride,
                           const float* __restrict__ bias,
                           OT* __restrict__ Out, int ldo,
                           const int4* __restrict__ ttab,
                           const int* __restrict__ tcount,
                           const int* __restrict__ perm,
                           int O, int relu) {
    int t = blockIdx.x;
    if (t >= *tcount) return;
    int4 tt = ttab[t];
    int a = tt.x, pos0 = tt.y;
    constexpr int JJ = 2 * NC;
    constexpr int NCH = 4 + 4 * NC;     // chunks per K-step
    constexpr int CPW = NCH / 4;        // chunks per wave

    __shared__ ushort_t S[2][NCH * 512];
    __shared__ ushort_t Cs[PACKOUT ? 64 * 136 : 2];

    int tid = threadIdx.x;
    int wave = tid >> 6, lane = tid & 63;
    int wr = (wave >> 1) & 1, wc = wave & 1;
    int quad = lane >> 4, l16 = lane & 15;

    int KK = K >> 5;

    const ushort_t* cbase[CPW];
    int cstep[CPW];
    #pragma unroll
    for (int q = 0; q < CPW; q++) {
        int c = wave * CPW + q;
        if (c < 4) {
            cbase[q] = Apk + ((long long)((pos0 >> 4) + c) * KK) * 512 + lane * 8;
            cstep[q] = 512;
        } else {
            int idx = c - 4, cblk = idx >> 2, su = idx & 3;
            cbase[q] = Wpk + (long long)a * wstride +
                (long long)(blockIdx.y * NC + cblk) * KK * 2048 + su * 512 + lane * 8;
            cstep[q] = 2048;
        }
    }
    auto STAGE = [&](int bufv, int kkv) {
        #pragma unroll
        for (int q = 0; q < CPW; q++)
            gl16(cbase[q] + kkv * cstep[q], &S[bufv][(wave * CPW + q) * 512]);
    };

    f32x4 acc[2][JJ];
    #pragma unroll
    for (int i = 0; i < 2; i++)
        #pragma unroll
        for (int j = 0; j < JJ; j++) acc[i][j] = (f32x4){0.f, 0.f, 0.f, 0.f};

    STAGE(0, 0);
    vm0_bar();
    int cur = 0;
    for (int kk = 0; kk < KK; kk++) {
        if (kk + 1 < KK) STAGE(cur ^ 1, kk + 1);
        const ushort_t* Sc = S[cur];
        bf16x8 af[2], bf[JJ];
        #pragma unroll
        for (int i = 0; i < 2; i++)
            af[i] = *(const bf16x8*)(Sc + (wr * 2 + i) * 512 + lane * 8);
        #pragma unroll
        for (int j = 0; j < JJ; j++) {
            int ch = (NC == 2) ? (4 + wc * 4 + j) : (4 + wc * 2 + j);
            bf[j] = *(const bf16x8*)(Sc + ch * 512 + lane * 8);
        }
        #pragma unroll
        for (int i = 0; i < 2; i++)
            #pragma unroll
            for (int j = 0; j < JJ; j++)
                acc[i][j] = __builtin_amdgcn_mfma_f32_16x16x32_bf16(af[i], bf[j], acc[i][j], 0, 0, 0);
        vm0_bar();
        cur ^= 1;
    }

    if constexpr (PACKOUT) {
        #pragma unroll
        for (int i = 0; i < 2; i++)
            #pragma unroll
            for (int j = 0; j < JJ; j++) {
                int colL = (NC == 2 ? wc * 64 : wc * 32) + j * 16 + l16;
                int col = blockIdx.y * (64 * NC) + colL;
                float bv = bias[col];
                #pragma unroll
                for (int r = 0; r < 4; r++) {
                    float v = acc[i][j][r] + bv;
                    if (relu) v = fmaxf(v, 0.f);
                    Cs[(wr * 32 + i * 16 + quad * 4 + r) * 136 + colL] = f2b(v);
                }
            }
        __syncthreads();
        int KKo = ldo >> 5;
        int kk0 = blockIdx.y * (2 * NC);
        constexpr int NKK = 2 * NC;
        #pragma unroll
        for (int s2 = 0; s2 < NKK; s2++) {
            int slot = s2 * 256 + tid;
            int l = slot & 63, t4 = slot >> 6;
            int mt = t4 / NKK, kkL = t4 - mt * NKK;
            us8 v = *(const us8*)(&Cs[(mt * 16 + (l & 15)) * 136 + kkL * 32 + (l >> 4) * 8]);
            *(us8*)((ushort_t*)Out + ((long long)((pos0 >> 4) + mt) * KKo + kk0 + kkL) * 512 + l * 8) = v;
        }
    } else {
        #pragma unroll
        for (int i = 0; i < 2; i++) {
            int mbase = wr * 32 + i * 16 + quad * 4;
            #pragma unroll
            for (int j = 0; j < JJ; j++) {
                int col = (NC == 2 ? wc * 64 : wc * 32) + j * 16 + l16;
                if (col < O) {
                    float bv = bias[col];
                    #pragma unroll
                    for (int r = 0; r < 4; r++) {
                        int pos = pos0 + mbase + r;
                        int orow = perm[pos];
                        if (orow < 8192) {
                            float v = acc[i][j][r] + bv;
                            if (relu) v = fmaxf(v, 0.f);
                            Out[(long long)orow * ldo + col] = v;
                        }
                    }
                }
            }
        }
    }
}

// ---------------------------------------------------------------------------
// Fused GRU — hybrid of measured-best halves:
//  * B path: baseline 2-barrier LDS staging (reg load -> ds_write -> ds_read),
//    shared across wr-waves. Proven 45.8 us structure.
//  * A path: direct packed-A global fragment loads (no LDS; packed-A IS
//    fragment order, verified R4). LDS drops 32->24 KB.
//  * Epilogue: gates + guarded out_h scatter + packed-A hp via LDS transpose
//    (Bt space reused after a barrier).
// acc0 = y.wih_r + h.whh_r ; acc1 = y.wih_z + h.whh_z ; acc2 = y.wih_n ;
// acc3 = h.whh_n.
// ---------------------------------------------------------------------------
__launch_bounds__(256, 3)
__global__ void gru_fused(const ushort_t* __restrict__ y1,       // packed-A
                          const ushort_t* __restrict__ hid,      // packed-A
                          const float* __restrict__ hidden_f,    // [N,H] orig fp32
                          const ushort_t* __restrict__ wihp,     // packed-B 3x(512,512)
                          const ushort_t* __restrict__ whhp,
                          const float* __restrict__ bih,
                          const float* __restrict__ bhh,
                          const int* __restrict__ perm,
                          float* __restrict__ out_h_f,           // [N,H] orig fp32
                          ushort_t* __restrict__ hp,             // packed-A out
                          const int4* __restrict__ ttab,
                          const int* __restrict__ tcount,
                          int H) {
    int t = blockIdx.x;
    if (t >= *tcount) return;
    int pos0 = ttab[t].y;
    int mt0 = pos0 >> 4;

    __shared__ ushort_t Bt[6][2048];     // 24 KB; reused as Cs in epilogue

    int tid = threadIdx.x;
    int wave = tid >> 6, lane = tid & 63;
    int wr = (wave >> 1) & 1, wc = wave & 1;
    int quad = lane >> 4, l16 = lane & 15;

    // packed-A bases: fragment (mt0 + u-tile, kk) at (mt0+u)*8192 + kk*512
    const ushort_t* ayp = y1 + (long long)mt0 * 8192 + lane * 8;
    const ushort_t* ahp = hid + (long long)mt0 * 8192 + lane * 8;

    // packed B tile stream bases (c-block = blockIdx.y): tile(kk) at kk*2048
    long long cb = (long long)blockIdx.y * 16 * 2048 + tid * 8;
    const ushort_t* wbg[6];
    #pragma unroll
    for (int g = 0; g < 3; g++) wbg[g] = wihp + (long long)g * 262144 + cb;
    #pragma unroll
    for (int g = 3; g < 6; g++) wbg[g] = whhp + (long long)(g - 3) * 262144 + cb;

    f32x4 acc[4][2][2];
    #pragma unroll
    for (int g = 0; g < 4; g++)
        #pragma unroll
        for (int i = 0; i < 2; i++)
            #pragma unroll
            for (int j = 0; j < 2; j++) acc[g][i][j] = (f32x4){0.f, 0.f, 0.f, 0.f};

    for (int kk = 0; kk < 16; kk++) {
        // direct packed-A fragment loads (drained by the barrier below)
        bf16x8 ayf[2], ahf[2];
        #pragma unroll
        for (int u = 0; u < 2; u++) {
            ayf[u] = *(const bf16x8*)(ayp + ((long long)(wr * 2 + u) * 16 + kk) * 512);
            ahf[u] = *(const bf16x8*)(ahp + ((long long)(wr * 2 + u) * 16 + kk) * 512);
        }
        us8 vb[6];
        #pragma unroll
        for (int g = 0; g < 6; g++) vb[g] = *(const us8*)(wbg[g] + kk * 2048);
        __syncthreads();
        #pragma unroll
        for (int g = 0; g < 6; g++) *(us8*)(&Bt[g][tid * 8]) = vb[g];
        __syncthreads();

        #pragma unroll
        for (int g = 0; g < 3; g++) {
            bf16x8 bw[2], bu[2];
            #pragma unroll
            for (int u = 0; u < 2; u++) {
                bw[u] = *(const bf16x8*)(&Bt[g][(wc * 2 + u) * 512 + lane * 8]);
                bu[u] = *(const bf16x8*)(&Bt[g + 3][(wc * 2 + u) * 512 + lane * 8]);
            }
            int ai = (g < 2) ? g : 2;   // ih products: r->0, z->1, n->2
            int ah2 = (g < 2) ? g : 3;  // hh products: r->0, z->1, n->3
            #pragma unroll
            for (int i = 0; i < 2; i++)
                #pragma unroll
                for (int j = 0; j < 2; j++) {
                    acc[ai][i][j] = __builtin_amdgcn_mfma_f32_16x16x32_bf16(
                        ayf[i], bw[j], acc[ai][i][j], 0, 0, 0);
                    acc[ah2][i][j] = __builtin_amdgcn_mfma_f32_16x16x32_bf16(
                        ahf[i], bu[j], acc[ah2][i][j], 0, 0, 0);
                }
        }
    }

    __syncthreads();                      // Bt reads done; reuse as Cs
    ushort_t* Cs = &Bt[0][0];             // 64 x 72 layout
    int c0 = blockIdx.y * 64;
    #pragma unroll
    for (int i = 0; i < 2; i++) {
        #pragma unroll
        for (int r = 0; r < 4; r++) {
            int rowL = wr * 32 + i * 16 + quad * 4 + r;
            int pos = pos0 + rowL;
            int norig = perm[pos];
            bool realr = norig < 8192;
            int nr = realr ? norig : 0;
            #pragma unroll
            for (int j = 0; j < 2; j++) {
                int colL = wc * 32 + j * 16 + l16;
                int col = c0 + colL;
                float sr = acc[0][i][j][r] + bih[col] + bhh[col];
                float sz = acc[1][i][j][r] + bih[H + col] + bhh[H + col];
                float in_ = acc[2][i][j][r] + bih[2 * H + col];
                float hn = acc[3][i][j][r] + bhh[2 * H + col];
                float rg = sigmoidf_(sr);
                float zg = sigmoidf_(sz);
                float ng = tanhf(in_ + rg * hn);
                float hv = hidden_f[(long long)nr * H + col];
                float hnew = (1.f - zg) * ng + zg * hv;
                if (realr) out_h_f[(long long)norig * H + col] = hnew;
                Cs[rowL * 72 + colL] = f2b(hnew);
            }
        }
    }
    __syncthreads();
    // packed-A store of hp: 4 mt x 2 kkL x 64 lanes = 512 slots, 2/thread
    #pragma unroll
    for (int s2 = 0; s2 < 2; s2++) {
        int slot = s2 * 256 + tid;
        int l = slot & 63, t4 = slot >> 6;
        int mt = t4 >> 1, kkL = t4 & 1;
        us8 v = *(const us8*)(&Cs[(mt * 16 + (l & 15)) * 72 + kkL * 32 + (l >> 4) * 8]);
        *(us8*)(hp + ((long long)(mt0 + mt) * 16 + blockIdx.y * 2 + kkL) * 512 + l * 8) = v;
    }
}

// ---------------------------------------------------------------------------
extern "C" void kernel_launch(void* const* d_in, const int* in_sizes, int n_in,
                              void* d_out, int out_size, void* d_ws, size_t ws_size,
                              hipStream_t stream) {
    (void)in_sizes; (void)n_in;
    const int N = 8192, A = 8, E = 64, H = 512, NA = 16;

    float* out_f = (float*)d_out;
    float* out_q = out_f;                        // [N, NA] fp32
    float* out_h = out_f + (size_t)N * NA;       // [N, H] fp32, original order

    char* p = (char*)d_ws;
    auto alloc = [&](size_t b) { char* r = p; p += (b + 255) & ~(size_t)255; return r; };
    int*  perm   = (int*)alloc((size_t)NPAD * 4);
    int*  seg    = (int*)alloc(16 * 4);
    int4* ttab   = (int4*)alloc(144 * 16);
    int*  tcount = (int*)alloc(256);
    ushort_t* wm1     = (ushort_t*)alloc((size_t)A * PACKSZ(H, E) * 2);
    ushort_t* wm2     = (ushort_t*)alloc((size_t)A * PACKSZ(H, H) * 2);
    ushort_t* wm3     = (ushort_t*)alloc((size_t)A * PACKSZ(H, H) * 2);
    ushort_t* wm4     = (ushort_t*)alloc((size_t)A * PACKSZ(NA, H) * 2);
    ushort_t* y1      = (ushort_t*)alloc((size_t)NPAD * H * 2);
    ushort_t* inp_pos = (ushort_t*)alloc((size_t)NPAD * E * 2);
    ushort_t* hid_pos = (ushort_t*)alloc((size_t)NPAD * H * 2);
    ushort_t* wihp    = (ushort_t*)alloc((size_t)3 * H * H * 2);
    ushort_t* whhp    = (ushort_t*)alloc((size_t)3 * H * H * 2);
    ushort_t* hp      = (ushort_t*)alloc((size_t)NPAD * H * 2);
    size_t need = (size_t)(p - (char*)d_ws);
    ushort_t* q2 = y1;       // alias: y1 dead after gru_fused
    ushort_t* q3 = hid_pos;  // alias: hid_pos dead after gru_fused

    if (ws_size < need) {
        fill_kernel<<<(unsigned)((out_size + 255) / 256), 256, 0, stream>>>(
            out_f, out_size, 1000.f);
        return;
    }

    const float* inputs = (const float*)d_in[0];
    const float* hidden = (const float*)d_in[1];
    const int*   ids    = (const int*)d_in[2];
    const float* fc1_w  = (const float*)d_in[3];
    const float* fc1_b  = (const float*)d_in[4];
    const float* fc1_al = (const float*)d_in[5];
    const float* wih    = (const float*)d_in[6];
    const float* whh    = (const float*)d_in[7];
    const float* bih    = (const float*)d_in[8];
    const float* bhh    = (const float*)d_in[9];
    const float* fc2_w  = (const float*)d_in[10];
    const float* fc2_b  = (const float*)d_in[11];
    const float* fc2_al = (const float*)d_in[12];
    const float* fc3_w  = (const float*)d_in[13];
    const float* fc3_b  = (const float*)d_in[14];
    const float* fc3_al = (const float*)d_in[15];
    const float* fc4_w  = (const float*)d_in[16];
    const float* fc4_b  = (const float*)d_in[17];
    const float* fc4_al = (const float*)d_in[18];

    sort_kernel<<<1, 1024, 0, stream>>>(ids, N, perm, seg, ttab, tcount);

    prep_kernel<<<PREP_BLOCKS, 256, 0, stream>>>(
        fc1_al, fc1_w, wm1, fc2_al, fc2_w, wm2, fc3_al, fc3_w, wm3,
        fc4_al, fc4_w, wm4, inputs, inp_pos, hidden, hid_pos,
        wih, wihp, whh, whhp, perm);

    dim3 blk(256);
    gemm_tiled<ushort_t, 2, 1><<<dim3(136, H / 128), blk, 0, stream>>>(
        inp_pos, E, wm1, PACKSZ(H, E), fc1_b, y1, H, ttab, tcount,
        perm, H, 1);
    gru_fused<<<dim3(136, H / 64), blk, 0, stream>>>(
        y1, hid_pos, hidden, wihp, whhp, bih, bhh, perm, out_h, hp,
        ttab, tcount, H);
    gemm_tiled<ushort_t, 2, 1><<<dim3(136, H / 128), blk, 0, stream>>>(
        hp, H, wm2, PACKSZ(H, H), fc2_b, q2, H, ttab, tcount,
        perm, H, 1);
    gemm_tiled<ushort_t, 2, 1><<<dim3(136, H / 128), blk, 0, stream>>>(
        q2, H, wm3, PACKSZ(H, H), fc3_b, q3, H, ttab, tcount,
        perm, H, 1);
    gemm_tiled<float, 1, 0><<<dim3(136, 1), blk, 0, stream>>>(
        q3, H, wm4, PACKSZ(NA, H), fc4_b, out_q, NA, ttab, tcount,
        perm, NA, 0);
}

// Round 8
// 221.947 us; speedup vs baseline: 1.2767x; 1.0794x over previous
//
#include <hip/hip_runtime.h>
#include <hip/hip_bf16.h>

typedef unsigned short ushort_t;
typedef __bf16 bf16x8 __attribute__((ext_vector_type(8)));
typedef unsigned short us8 __attribute__((ext_vector_type(8)));
typedef float f32x4 __attribute__((ext_vector_type(4)));

__device__ __forceinline__ ushort_t f2b(float f) {
    union { float f; unsigned int u; } v; v.f = f;
    unsigned int u = v.u;
    unsigned int r = (u + 0x7FFFu + ((u >> 16) & 1u)) >> 16;
    return (ushort_t)r;
}
__device__ __forceinline__ float sigmoidf_(float x) {
    return 1.f / (1.f + __expf(-x));
}
__device__ __forceinline__ void store_o(ushort_t* p, float v) { *p = f2b(v); }
__device__ __forceinline__ void store_o(float* p, float v) { *p = v; }

__global__ void fill_kernel(float* out, long long n, float val) {
    long long i = (long long)blockIdx.x * blockDim.x + threadIdx.x;
    if (i < n) out[i] = val;
}

// ---------------------------------------------------------------------------
// Packed B layout for mfma_f32_16x16x32_bf16 (per 64-col block c, 32-k group
// kk): 4 col-subtiles su, 64 lanes (lane = k-oct*16 + col&15), 8 bf16.
// Tile (c,kk) = 2048 ushorts; wave fragment load = 1 KB contiguous.
// ---------------------------------------------------------------------------
#define PACKSZ(O, K) ((long long)((O) >= 64 ? (O) >> 6 : 1) * ((K) >> 5) * 2048)

// ---------------------------------------------------------------------------
// Ballot-based sort: 1 block, 1024 thr (16 waves x 512 elems).
// ---------------------------------------------------------------------------
__global__ void sort_kernel(const int* __restrict__ ids, int N,
                            int* __restrict__ perm, int* __restrict__ seg,
                            int4* __restrict__ ttab, int* __restrict__ tcount) {
    __shared__ int hist[16][8];
    __shared__ int wbase[16][8];
    __shared__ int atot[8];
    __shared__ int abase[8];
    int tid = threadIdx.x, wave = tid >> 6, lane = tid & 63;
    int base = wave * 512;
    unsigned long long lt = (lane == 63) ? 0x7fffffffffffffffull
                                         : ((1ull << lane) - 1ull);
    int myid[8], rank[8];
    int run[8] = {0, 0, 0, 0, 0, 0, 0, 0};
    #pragma unroll
    for (int i = 0; i < 8; i++) myid[i] = ids[base + i * 64 + lane] & 7;
    #pragma unroll
    for (int i = 0; i < 8; i++) {
        int a = myid[i];
        int r = 0;
        #pragma unroll
        for (int a2 = 0; a2 < 8; a2++) {
            unsigned long long m = __ballot(a == a2);
            if (a2 == a) r = run[a2] + __popcll(m & lt);
            run[a2] += __popcll(m);
        }
        rank[i] = r;
    }
    if (lane == 0) {
        #pragma unroll
        for (int a = 0; a < 8; a++) hist[wave][a] = run[a];
    }
    __syncthreads();
    if (tid < 8) {
        int a = tid, s = 0;
        for (int w = 0; w < 16; w++) { wbase[w][a] = s; s += hist[w][a]; }
        atot[a] = s;
    }
    __syncthreads();
    if (tid == 0) {
        int s = 0;
        for (int a = 0; a < 8; a++) { abase[a] = s; seg[a] = s; s += atot[a]; }
        seg[8] = s;
        int T = 0;
        for (int a = 0; a < 8; a++)
            for (int m = abase[a]; m < abase[a] + atot[a]; m += 64) {
                int e = abase[a] + atot[a];
                if (e > m + 64) e = m + 64;
                ttab[T++] = make_int4(a, m, e, 0);
            }
        *tcount = T;
    }
    __syncthreads();
    #pragma unroll
    for (int i = 0; i < 8; i++) {
        int a = myid[i];
        perm[abase[a] + wbase[wave][a] + rank[i]] = base + i * 64 + lane;
    }
}

// ---------------------------------------------------------------------------
// Fused prep: masked weights -> packed-B bf16; activations gathered to
// pos-order bf16; GRU weights -> packed-B bf16.
// ---------------------------------------------------------------------------
__device__ __forceinline__ void maskw_item(const float* __restrict__ alpha,
                                           const float* __restrict__ w,
                                           ushort_t* __restrict__ wm,
                                           long long idx, int O, int G, int dup) {
    int g = (int)(idx % G);
    long long t2 = idx / G;
    int o = (int)(t2 % O);
    int a = (int)(t2 / O);
    const float* al = alpha + idx * 6;
    float p[6];
    float mx = -1e30f;
    #pragma unroll
    for (int i = 0; i < 6; i++) { p[i] = al[i] * 0.2f; mx = fmaxf(mx, p[i]); }
    float s = 0.f;
    #pragma unroll
    for (int i = 0; i < 6; i++) { p[i] = __expf(p[i] - mx); s += p[i]; }
    float inv = 1.f / s;
    #pragma unroll
    for (int i = 0; i < 6; i++) p[i] *= inv;
    float mk[4] = { p[0] + p[1] + p[2], p[0] + p[3] + p[4],
                    p[1] + p[3] + p[5], p[2] + p[4] + p[5] };
    int K = G * 4;
    const float* wr = w + (long long)o * K + g * 4;
    ushort_t* base = wm + (long long)a * PACKSZ(O, K);
    int k0 = g * 4;
    int c = o >> 6, su = (o >> 4) & 3, n = o & 15;
    int kk = k0 >> 5, q = (k0 >> 3) & 3, e0 = k0 & 7;
    long long off = (((long long)(c * (K >> 5) + kk) * 4 + su) * 64 + (q * 16 + n)) * 8 + e0;
    #pragma unroll
    for (int t = 0; t < 4; t++) {
        ushort_t v = f2b(wr[t] * mk[t]);
        base[off + t] = v;
        if (dup) {
            base[off + t + 512] = v;
            base[off + t + 1024] = v;
            base[off + t + 1536] = v;
        }
    }
}

__device__ __forceinline__ void canon_gather_item(const float* __restrict__ src,
                                                  ushort_t* __restrict__ dst,
                                                  const int* __restrict__ perm,
                                                  int ld, long long i) {
    long long base = i * 8;
    int pos = (int)(base / ld);
    int k = (int)(base % ld);
    int row = perm[pos] & 8191;
    const float* s = src + (long long)row * ld + k;
    us8 v;
    #pragma unroll
    for (int e = 0; e < 8; e++) v[e] = f2b(s[e]);
    *(us8*)(dst + base) = v;
}

__device__ __forceinline__ void canon_pack_item(const float* __restrict__ src,
                                                ushort_t* __restrict__ dst,
                                                long long i) {
    long long base = i * 8;
    int o_full = (int)(base >> 9);
    int k0 = (int)(base & 511);
    int g = o_full >> 9, o = o_full & 511;
    int c = o >> 6, su = (o >> 4) & 3, n = o & 15;
    int kk = k0 >> 5, q = (k0 >> 3) & 3;
    long long off = (long long)g * 262144 +
        (((long long)(c * 16 + kk) * 4 + su) * 64 + (q * 16 + n)) * 8;
    us8 v;
    #pragma unroll
    for (int e = 0; e < 8; e++) v[e] = f2b(src[base + e]);
    *(us8*)(dst + off) = v;
}

#define PB0 256
#define PB1 2048
#define PB2 2048
#define PB3 64
#define PB4 256
#define PB5 2048
#define PB6 384
#define PB7 384
#define PREP_BLOCKS (PB0+PB1+PB2+PB3+PB4+PB5+PB6+PB7)

__global__ void prep_kernel(const float* fc1_al, const float* fc1_w, ushort_t* wm1,
                            const float* fc2_al, const float* fc2_w, ushort_t* wm2,
                            const float* fc3_al, const float* fc3_w, ushort_t* wm3,
                            const float* fc4_al, const float* fc4_w, ushort_t* wm4,
                            const float* inputs, ushort_t* inp_pos,
                            const float* hidden, ushort_t* hid_pos,
                            const float* wih, ushort_t* wihp,
                            const float* whh, ushort_t* whhp,
                            const int* perm) {
    int b = blockIdx.x;
    int tid = threadIdx.x;
    if (b < PB0) { maskw_item(fc1_al, fc1_w, wm1, (long long)b * 256 + tid, 512, 16, 0); return; }
    b -= PB0;
    if (b < PB1) { maskw_item(fc2_al, fc2_w, wm2, (long long)b * 256 + tid, 512, 128, 0); return; }
    b -= PB1;
    if (b < PB2) { maskw_item(fc3_al, fc3_w, wm3, (long long)b * 256 + tid, 512, 128, 0); return; }
    b -= PB2;
    if (b < PB3) { maskw_item(fc4_al, fc4_w, wm4, (long long)b * 256 + tid, 16, 128, 1); return; }
    b -= PB3;
    if (b < PB4) { canon_gather_item(inputs, inp_pos, perm, 64, (long long)b * 256 + tid); return; }
    b -= PB4;
    if (b < PB5) { canon_gather_item(hidden, hid_pos, perm, 512, (long long)b * 256 + tid); return; }
    b -= PB5;
    if (b < PB6) { canon_pack_item(wih, wihp, (long long)b * 256 + tid); return; }
    b -= PB6;
    canon_pack_item(whh, whhp, (long long)b * 256 + tid);
}

// ---------------------------------------------------------------------------
// GEMM: baseline structure, 2-kk unrolled: 8 MFMA per barrier-pair (was 4),
// barrier-pairs halved. A staged via swizzled LDS (2 buffers); B streamed
// from packed global per wave. All K here have even KK (2 or 16).
// ---------------------------------------------------------------------------
#define BM 64
#define BN 64

template <typename OT>
__launch_bounds__(256, 4)
__global__ void gemm_tiled(const ushort_t* __restrict__ In, int ldin,
                           const ushort_t* __restrict__ Wpk, long long wstride,
                           const float* __restrict__ bias,
                           OT* __restrict__ Out, int ldo,
                           const int4* __restrict__ ttab,
                           const int* __restrict__ tcount,
                           const int* __restrict__ scatter,
                           int O, int K, int relu) {
    int t = blockIdx.x;
    if (t >= *tcount) return;
    int4 tt = ttab[t];
    int a = tt.x, pos0 = tt.y, pos1 = tt.z;
    int o0 = blockIdx.y * BN;

    __shared__ ushort_t As[2][2048];

    int tid = threadIdx.x;
    int wave = tid >> 6, lane = tid & 63;
    int wr = (wave >> 1) & 1, wc = wave & 1;
    int quad = lane >> 4, l16 = lane & 15;
    int srow = tid >> 2, sgrp = tid & 3;
    int wsoff = (srow * 4 + (sgrp ^ ((srow >> 2) & 3))) * 8;
    int rl = (l16 * 4 + (quad ^ ((l16 >> 2) & 3))) * 8;

    int apos = pos0 + srow;
    int apos_c = apos < pos1 ? apos : (pos1 - 1);
    const ushort_t* aptr = In + (long long)apos_c * ldin + sgrp * 8;

    const ushort_t* wb = Wpk + (long long)a * wstride +
        (long long)blockIdx.y * (K >> 5) * 2048 + lane * 8;

    f32x4 acc[2][2];
    #pragma unroll
    for (int i = 0; i < 2; i++)
        #pragma unroll
        for (int j = 0; j < 2; j++) acc[i][j] = (f32x4){0.f, 0.f, 0.f, 0.f};

    int KKh = K >> 6;    // pairs of 32-k groups
    for (int k2 = 0; k2 < KKh; k2++) {
        int kk = k2 * 2;
        us8 av0 = *(const us8*)(aptr + kk * 32);
        us8 av1 = *(const us8*)(aptr + kk * 32 + 32);
        bf16x8 b00 = *(const bf16x8*)(wb + (kk * 4 + wc * 2 + 0) * 512);
        bf16x8 b01 = *(const bf16x8*)(wb + (kk * 4 + wc * 2 + 1) * 512);
        bf16x8 b10 = *(const bf16x8*)(wb + ((kk + 1) * 4 + wc * 2 + 0) * 512);
        bf16x8 b11 = *(const bf16x8*)(wb + ((kk + 1) * 4 + wc * 2 + 1) * 512);
        __syncthreads();
        *(us8*)(&As[0][wsoff]) = av0;
        *(us8*)(&As[1][wsoff]) = av1;
        __syncthreads();
        bf16x8 af0[2], af1[2];
        af0[0] = *(const bf16x8*)(&As[0][(wr * 2 + 0) * 512 + rl]);
        af0[1] = *(const bf16x8*)(&As[0][(wr * 2 + 1) * 512 + rl]);
        af1[0] = *(const bf16x8*)(&As[1][(wr * 2 + 0) * 512 + rl]);
        af1[1] = *(const bf16x8*)(&As[1][(wr * 2 + 1) * 512 + rl]);
        #pragma unroll
        for (int i = 0; i < 2; i++) {
            acc[i][0] = __builtin_amdgcn_mfma_f32_16x16x32_bf16(af0[i], b00, acc[i][0], 0, 0, 0);
            acc[i][1] = __builtin_amdgcn_mfma_f32_16x16x32_bf16(af0[i], b01, acc[i][1], 0, 0, 0);
        }
        #pragma unroll
        for (int i = 0; i < 2; i++) {
            acc[i][0] = __builtin_amdgcn_mfma_f32_16x16x32_bf16(af1[i], b10, acc[i][0], 0, 0, 0);
            acc[i][1] = __builtin_amdgcn_mfma_f32_16x16x32_bf16(af1[i], b11, acc[i][1], 0, 0, 0);
        }
    }

    #pragma unroll
    for (int i = 0; i < 2; i++) {
        int mbase = wr * 32 + i * 16 + quad * 4;
        #pragma unroll
        for (int j = 0; j < 2; j++) {
            int col = o0 + wc * 32 + j * 16 + l16;
            if (col < O) {
                float bias_v = bias ? bias[col] : 0.f;
                #pragma unroll
                for (int r = 0; r < 4; r++) {
                    int pos = pos0 + mbase + r;
                    if (pos < pos1) {
                        float v = acc[i][j][r] + bias_v;
                        if (relu) v = fmaxf(v, 0.f);
                        int orow = (scatter ? scatter[pos] : pos) & 8191;
                        store_o(&Out[(long long)orow * ldo + col], v);
                    }
                }
            }
        }
    }
}

// ---------------------------------------------------------------------------
// Fused GRU, baseline 2-barrier structure widened to BM=128 (512 thr, 8
// waves: wr in 0..3 over rows, wc in 0..1 over cols). The 24 KB B tile now
// serves 128 rows -> B L2 traffic halves. Same acc footprint per wave.
//   acc0 = y1.wih_r + h.whh_r ; acc1 = y1.wih_z + h.whh_z
//   acc2 = y1.wih_n           ; acc3 = h.whh_n
// ---------------------------------------------------------------------------
__launch_bounds__(512, 2)
__global__ void gru_fused(const ushort_t* __restrict__ y1,       // [N,H] pos bf16
                          const ushort_t* __restrict__ hid_pos,  // [N,H] pos bf16
                          const float* __restrict__ hidden_f,    // [N,H] orig fp32
                          const ushort_t* __restrict__ wihp,     // packed 3x(512,512)
                          const ushort_t* __restrict__ whhp,     // packed 3x(512,512)
                          const float* __restrict__ bih,
                          const float* __restrict__ bhh,
                          const int* __restrict__ perm,
                          float* __restrict__ out_h_f,           // [N,H] orig fp32
                          ushort_t* __restrict__ hp,             // [N,H] pos bf16
                          int N, int H) {
    int m0 = blockIdx.x * 128;

    __shared__ ushort_t Ay[4096];
    __shared__ ushort_t Ah[4096];
    __shared__ ushort_t Bt[6][2048];

    int tid = threadIdx.x;
    int wave = tid >> 6, lane = tid & 63;
    int wr = wave >> 1, wc = wave & 1;          // wr 0..3, wc 0..1
    int quad = lane >> 4, l16 = lane & 15;
    int srow = tid >> 2, sgrp = tid & 3;        // srow 0..127
    int wsoff = (srow * 4 + (sgrp ^ ((srow >> 2) & 3))) * 8;
    int rl = (l16 * 4 + (quad ^ ((l16 >> 2) & 3))) * 8;

    const ushort_t* ay_p = y1 + (long long)(m0 + srow) * H + sgrp * 8;
    const ushort_t* ah_p = hid_pos + (long long)(m0 + srow) * H + sgrp * 8;

    // B staging: 1536 us8 slots (6 tiles x 256), 3 per thread: s = q*512+tid
    const ushort_t* wbs[3];
    int wg[3];
    #pragma unroll
    for (int q = 0; q < 3; q++) {
        int s = q * 512 + tid;
        int g = s >> 8, so = s & 255;
        wg[q] = s;
        wbs[q] = ((g < 3) ? (wihp + (long long)g * 262144)
                          : (whhp + (long long)(g - 3) * 262144)) +
                 (long long)blockIdx.y * 16 * 2048 + so * 8;
    }

    f32x4 acc[4][2][2];
    #pragma unroll
    for (int g = 0; g < 4; g++)
        #pragma unroll
        for (int i = 0; i < 2; i++)
            #pragma unroll
            for (int j = 0; j < 2; j++) acc[g][i][j] = (f32x4){0.f, 0.f, 0.f, 0.f};

    for (int kk = 0; kk < 16; kk++) {
        us8 va = *(const us8*)(ay_p + kk * 32);
        us8 vh = *(const us8*)(ah_p + kk * 32);
        us8 vb[3];
        #pragma unroll
        for (int q = 0; q < 3; q++) vb[q] = *(const us8*)(wbs[q] + kk * 2048);
        __syncthreads();
        *(us8*)(&Ay[wsoff]) = va;
        *(us8*)(&Ah[wsoff]) = vh;
        #pragma unroll
        for (int q = 0; q < 3; q++) {
            int s = wg[q];
            *(us8*)(&Bt[s >> 8][(s & 255) * 8]) = vb[q];
        }
        __syncthreads();

        bf16x8 ayf[2], ahf[2];
        #pragma unroll
        for (int u = 0; u < 2; u++) {
            ayf[u] = *(const bf16x8*)(&Ay[(wr * 2 + u) * 512 + rl]);
            ahf[u] = *(const bf16x8*)(&Ah[(wr * 2 + u) * 512 + rl]);
        }
        #pragma unroll
        for (int g = 0; g < 3; g++) {
            bf16x8 bw[2], bu[2];
            #pragma unroll
            for (int u = 0; u < 2; u++) {
                bw[u] = *(const bf16x8*)(&Bt[g][(wc * 2 + u) * 512 + lane * 8]);
                bu[u] = *(const bf16x8*)(&Bt[g + 3][(wc * 2 + u) * 512 + lane * 8]);
            }
            int ai = (g < 2) ? g : 2;   // ih products: r->0, z->1, n->2
            int ah2 = (g < 2) ? g : 3;  // hh products: r->0, z->1, n->3
            #pragma unroll
            for (int i = 0; i < 2; i++)
                #pragma unroll
                for (int j = 0; j < 2; j++) {
                    acc[ai][i][j] = __builtin_amdgcn_mfma_f32_16x16x32_bf16(
                        ayf[i], bw[j], acc[ai][i][j], 0, 0, 0);
                    acc[ah2][i][j] = __builtin_amdgcn_mfma_f32_16x16x32_bf16(
                        ahf[i], bu[j], acc[ah2][i][j], 0, 0, 0);
                }
        }
    }

    int c0 = blockIdx.y * 64;
    #pragma unroll
    for (int i = 0; i < 2; i++) {
        #pragma unroll
        for (int r = 0; r < 4; r++) {
            int pos = m0 + wr * 32 + i * 16 + quad * 4 + r;
            int norig = perm[pos] & 8191;
            #pragma unroll
            for (int j = 0; j < 2; j++) {
                int col = c0 + wc * 32 + j * 16 + l16;
                float sr = acc[0][i][j][r] + bih[col] + bhh[col];
                float sz = acc[1][i][j][r] + bih[H + col] + bhh[H + col];
                float in_ = acc[2][i][j][r] + bih[2 * H + col];
                float hn = acc[3][i][j][r] + bhh[2 * H + col];
                float rg = sigmoidf_(sr);
                float zg = sigmoidf_(sz);
                float ng = tanhf(in_ + rg * hn);
                float hv = hidden_f[(long long)norig * H + col];
                float hnew = (1.f - zg) * ng + zg * hv;
                out_h_f[(long long)norig * H + col] = hnew;
                hp[(long long)pos * H + col] = f2b(hnew);
            }
        }
    }
}

// ---------------------------------------------------------------------------
extern "C" void kernel_launch(void* const* d_in, const int* in_sizes, int n_in,
                              void* d_out, int out_size, void* d_ws, size_t ws_size,
                              hipStream_t stream) {
    (void)in_sizes; (void)n_in;
    const int N = 8192, A = 8, E = 64, H = 512, NA = 16;

    float* out_f = (float*)d_out;
    float* out_q = out_f;                        // [N, NA] fp32
    float* out_h = out_f + (size_t)N * NA;       // [N, H] fp32, original order

    char* p = (char*)d_ws;
    auto alloc = [&](size_t b) { char* r = p; p += (b + 255) & ~(size_t)255; return r; };
    int*  perm   = (int*)alloc((size_t)N * 4);
    int*  seg    = (int*)alloc(16 * 4);
    int4* ttab   = (int4*)alloc(144 * 16);
    int*  tcount = (int*)alloc(256);
    ushort_t* wm1     = (ushort_t*)alloc((size_t)A * PACKSZ(H, E) * 2);
    ushort_t* wm2     = (ushort_t*)alloc((size_t)A * PACKSZ(H, H) * 2);
    ushort_t* wm3     = (ushort_t*)alloc((size_t)A * PACKSZ(H, H) * 2);
    ushort_t* wm4     = (ushort_t*)alloc((size_t)A * PACKSZ(NA, H) * 2);
    ushort_t* y1      = (ushort_t*)alloc((size_t)N * H * 2);
    ushort_t* inp_pos = (ushort_t*)alloc((size_t)N * E * 2);
    ushort_t* hid_pos = (ushort_t*)alloc((size_t)N * H * 2);
    ushort_t* wihp    = (ushort_t*)alloc((size_t)3 * H * H * 2);
    ushort_t* whhp    = (ushort_t*)alloc((size_t)3 * H * H * 2);
    ushort_t* hp      = (ushort_t*)alloc((size_t)N * H * 2);
    size_t need = (size_t)(p - (char*)d_ws);
    ushort_t* q2 = y1;       // alias: y1 dead after gru_fused
    ushort_t* q3 = hid_pos;  // alias: hid_pos dead after gru_fused

    if (ws_size < need) {
        fill_kernel<<<(unsigned)((out_size + 255) / 256), 256, 0, stream>>>(
            out_f, out_size, 1000.f);
        return;
    }

    const float* inputs = (const float*)d_in[0];
    const float* hidden = (const float*)d_in[1];
    const int*   ids    = (const int*)d_in[2];
    const float* fc1_w  = (const float*)d_in[3];
    const float* fc1_b  = (const float*)d_in[4];
    const float* fc1_al = (const float*)d_in[5];
    const float* wih    = (const float*)d_in[6];
    const float* whh    = (const float*)d_in[7];
    const float* bih    = (const float*)d_in[8];
    const float* bhh    = (const float*)d_in[9];
    const float* fc2_w  = (const float*)d_in[10];
    const float* fc2_b  = (const float*)d_in[11];
    const float* fc2_al = (const float*)d_in[12];
    const float* fc3_w  = (const float*)d_in[13];
    const float* fc3_b  = (const float*)d_in[14];
    const float* fc3_al = (const float*)d_in[15];
    const float* fc4_w  = (const float*)d_in[16];
    const float* fc4_b  = (const float*)d_in[17];
    const float* fc4_al = (const float*)d_in[18];

    sort_kernel<<<1, 1024, 0, stream>>>(ids, N, perm, seg, ttab, tcount);

    prep_kernel<<<PREP_BLOCKS, 256, 0, stream>>>(
        fc1_al, fc1_w, wm1, fc2_al, fc2_w, wm2, fc3_al, fc3_w, wm3,
        fc4_al, fc4_w, wm4, inputs, inp_pos, hidden, hid_pos,
        wih, wihp, whh, whhp, perm);

    dim3 blk(256);
    gemm_tiled<ushort_t><<<dim3(136, H / BN), blk, 0, stream>>>(
        inp_pos, E, wm1, PACKSZ(H, E), fc1_b, y1, H, ttab, tcount,
        nullptr, H, E, 1);
    gru_fused<<<dim3(N / 128, H / 64), dim3(512), 0, stream>>>(
        y1, hid_pos, hidden, wihp, whhp, bih, bhh, perm, out_h, hp, N, H);
    gemm_tiled<ushort_t><<<dim3(136, H / BN), blk, 0, stream>>>(
        hp, H, wm2, PACKSZ(H, H), fc2_b, q2, H, ttab, tcount,
        nullptr, H, H, 1);
    gemm_tiled<ushort_t><<<dim3(136, H / BN), blk, 0, stream>>>(
        q2, H, wm3, PACKSZ(H, H), fc3_b, q3, H, ttab, tcount,
        nullptr, H, H, 1);
    gemm_tiled<float><<<dim3(136, 1), blk, 0, stream>>>(
        q3, H, wm4, PACKSZ(NA, H), fc4_b, out_q, NA, ttab, tcount,
        perm, NA, H, 0);
}